// Round 6
// baseline (197.231 us; speedup 1.0000x reference)
//
#include <hip/hip_runtime.h>
#include <hip/hip_bf16.h>

#define NIN 1024
#define NOUT 4096
#define NTOK 4096
#define NSTACK 4
#define RANK 4

typedef __bf16 bf16x8 __attribute__((ext_vector_type(8)));
typedef float f32x4 __attribute__((ext_vector_type(4)));

// ============ fused prep ============
// blocks 0..2046: build M — block bid = diagonal bid, wave w = stack w.
//   Lane owns 16 consecutive elements of the diagonal: segment-sum -> one
//   wave scan (6 shfl) -> re-walk & store. No barriers, no serial chunk loop.
// blocks 2047..4094: cast x fp32->bf16 (2048 blocks).
//
// M[s,t,c] = prefix along diagonal of E[t][c] = sum_r G_r[t]*H_r[c].
__global__ __launch_bounds__(256) void prep_kernel(const float* __restrict__ x,
                                                   const float* __restrict__ G,
                                                   const float* __restrict__ H,
                                                   __bf16* __restrict__ xb,
                                                   __bf16* __restrict__ M) {
  int bid = blockIdx.x;
  if (bid >= 2047) {  // -------- cast --------
    int i = ((bid - 2047) * 256 + threadIdx.x) * 8;
    float4 a = *reinterpret_cast<const float4*>(x + i);
    float4 b = *reinterpret_cast<const float4*>(x + i + 4);
    bf16x8 o;
    o[0] = (__bf16)a.x; o[1] = (__bf16)a.y; o[2] = (__bf16)a.z; o[3] = (__bf16)a.w;
    o[4] = (__bf16)b.x; o[5] = (__bf16)b.y; o[6] = (__bf16)b.z; o[7] = (__bf16)b.w;
    *reinterpret_cast<bf16x8*>(xb + i) = o;
    return;
  }
  // -------- build M: wave = (stack w, diagonal bid) --------
  const int w = threadIdx.x >> 6;        // stack
  const int lane = threadIdx.x & 63;
  const int d = bid - 1023;              // d = c - t, in [-1023, 1023]
  const int gofs = d < 0 ? -d : 0;
  const int hofs = d > 0 ? d : 0;
  const int L = NIN - (d < 0 ? -d : d);
  const float* Gs = G + w * (RANK * NIN);
  const float* Hs = H + w * (RANK * NIN);
  __bf16* Ms = M + (size_t)w * NIN * NIN;

  const int k0 = lane * 16;
  float e[16];
  float ssum = 0.f;
  #pragma unroll
  for (int i = 0; i < 16; ++i) {
    const int k = k0 + i;
    float v = 0.f;
    if (k < L) {
      const int t = k + gofs, c = k + hofs;
      v = Gs[t] * Hs[c] + Gs[NIN + t] * Hs[NIN + c]
        + Gs[2 * NIN + t] * Hs[2 * NIN + c] + Gs[3 * NIN + t] * Hs[3 * NIN + c];
    }
    e[i] = v;
    ssum += v;
  }
  // wave inclusive scan of per-lane segment sums
  float incl = ssum;
  #pragma unroll
  for (int off = 1; off < 64; off <<= 1) {
    float o = __shfl_up(incl, off, 64);
    if (lane >= off) incl += o;
  }
  float acc = incl - ssum;  // exclusive prefix
  #pragma unroll
  for (int i = 0; i < 16; ++i) {
    const int k = k0 + i;
    acc += e[i];
    if (k < L) {
      const int t = k + gofs, c = k + hofs;
      Ms[(size_t)t * NIN + c] = (__bf16)acc;
    }
  }
}

// ============ GEMM: C[m][n] = sum_k A[m][k]*B[n][k] + bias[n] ============
// 128x128 tile, BK=64, 256 thr / 4 waves (2x2, wave tile 64x64).
// Double-buffered 64KB LDS -> 2 blocks/CU (cross-block overlap covers stalls).
// Counted vmcnt(8) per K-tile (drain only on last). Swizzle for 128B rows:
// inner ^= (row&7)<<4 (uniform 8 lanes/16B-slot => structural optimum).
#define GBK 64
#define GKT (NIN / GBK)     // 16
#define BUFSZ 32768         // A 16K + B 16K

__device__ __forceinline__ void gload16(const char* gsrc, char* lds) {
  __builtin_amdgcn_global_load_lds(
      (const __attribute__((address_space(1))) unsigned int*)gsrc,
      (__attribute__((address_space(3))) unsigned int*)lds, 16, 0, 0);
}

__global__ __launch_bounds__(256, 2) void gemm_kernel(
    const __bf16* __restrict__ A,   // [NTOK][NIN]
    const __bf16* __restrict__ B,   // [NOUT][NIN]
    const float* __restrict__ bias, // [NOUT]
    float* __restrict__ C) {        // [NTOK][NOUT]
  __shared__ __align__(16) char smem[2 * BUFSZ];  // 64 KB

  const int tid = threadIdx.x;
  const int lane = tid & 63;
  const int lo = lane & 15;
  const int hi = lane >> 4;
  const int wid = tid >> 6;
  const int wr = wid >> 1;   // 0..1
  const int wc = wid & 1;    // 0..1

  // XCD-aware swizzle (grid 1024, 1024%8==0)
  const int orig = blockIdx.x;
  const int wg = (orig & 7) * 128 + (orig >> 3);
  const int bx = wg & 31;
  const int by = wg >> 5;
  const int brow = by * 128;
  const int bcol = bx * 128;

  const char* Ab = (const char*)A + (size_t)brow * (NIN * 2);
  const char* Bb = (const char*)B + (size_t)bcol * (NIN * 2);

  // staging: per thread 4 A + 4 B gloads per K-tile. LDS dest linear;
  // global source pre-swizzled: inner ^ ((row&7)<<4)  [both-sides rule 21]
  int lofs[4];
  size_t gofs2[4];
  #pragma unroll
  for (int l = 0; l < 4; ++l) {
    const int P = tid * 16 + l * 4096;   // 0..16383
    const int row = P >> 7;              // 0..127
    const int inner = (P & 127) ^ ((row & 7) << 4);
    lofs[l] = P;
    gofs2[l] = (size_t)row * (NIN * 2) + inner;
  }

  // fragment ds_read byte offsets (swizzled read side), row&7 == lo&7
  int aoff[4][2], boff[4][2];
  #pragma unroll
  for (int mi = 0; mi < 4; ++mi)
    #pragma unroll
    for (int ks = 0; ks < 2; ++ks) {
      const int kin = (ks * 64 + hi * 16) ^ ((lo & 7) << 4);
      aoff[mi][ks] = (wr * 64 + mi * 16 + lo) * 128 + kin;
      boff[mi][ks] = 16384 + (wc * 64 + mi * 16 + lo) * 128 + kin;
    }

  f32x4 acc[4][4];
  #pragma unroll
  for (int i = 0; i < 4; ++i)
    #pragma unroll
    for (int j = 0; j < 4; ++j)
      acc[i][j] = (f32x4){0.f, 0.f, 0.f, 0.f};

  // prologue: stage tile 0 -> buf 0
  #pragma unroll
  for (int l = 0; l < 4; ++l) gload16(Ab + gofs2[l], smem + lofs[l]);
  #pragma unroll
  for (int l = 0; l < 4; ++l) gload16(Bb + gofs2[l], smem + 16384 + lofs[l]);

  #pragma unroll 1
  for (int kt = 0; kt < GKT; ++kt) {
    // stage next tile (safe: all waves passed bottom barrier of kt-1,
    // which guaranteed reads of buf^1 (tile kt-1) were complete)
    if (kt < GKT - 1) {
      char* sb = smem + ((kt + 1) & 1) * BUFSZ;
      const int kb = (kt + 1) * 128;
      #pragma unroll
      for (int l = 0; l < 4; ++l) gload16(Ab + kb + gofs2[l], sb + lofs[l]);
      #pragma unroll
      for (int l = 0; l < 4; ++l) gload16(Bb + kb + gofs2[l], sb + 16384 + lofs[l]);
      asm volatile("s_waitcnt vmcnt(8)" ::: "memory");  // tile kt resident
    } else {
      asm volatile("s_waitcnt vmcnt(0)" ::: "memory");
    }
    __builtin_amdgcn_s_barrier();

    const char* buf = smem + (kt & 1) * BUFSZ;
    #pragma unroll
    for (int ks = 0; ks < 2; ++ks) {
      bf16x8 af[4], bfr[4];
      #pragma unroll
      for (int mi = 0; mi < 4; ++mi)
        af[mi] = *(const bf16x8*)(buf + aoff[mi][ks]);
      #pragma unroll
      for (int ni = 0; ni < 4; ++ni)
        bfr[ni] = *(const bf16x8*)(buf + boff[ni][ks]);
      __builtin_amdgcn_s_setprio(1);
      #pragma unroll
      for (int mi = 0; mi < 4; ++mi)
        #pragma unroll
        for (int ni = 0; ni < 4; ++ni)
          acc[mi][ni] = __builtin_amdgcn_mfma_f32_16x16x32_bf16(af[mi], bfr[ni], acc[mi][ni], 0, 0, 0);
      __builtin_amdgcn_s_setprio(0);
    }
    __builtin_amdgcn_s_barrier();
  }

  // epilogue: D layout col=lane&15, row=(lane>>4)*4+reg
  #pragma unroll
  for (int ni = 0; ni < 4; ++ni) {
    const int col = bcol + wc * 64 + ni * 16 + lo;
    const float bv = bias[col];
    #pragma unroll
    for (int mi = 0; mi < 4; ++mi) {
      const int row0 = brow + wr * 64 + mi * 16 + hi * 4;
      float* Cp = C + (size_t)row0 * NOUT + col;
      Cp[0]                = acc[mi][ni][0] + bv;
      Cp[(size_t)NOUT]     = acc[mi][ni][1] + bv;
      Cp[2 * (size_t)NOUT] = acc[mi][ni][2] + bv;
      Cp[3 * (size_t)NOUT] = acc[mi][ni][3] + bv;
    }
  }
}

extern "C" void kernel_launch(void* const* d_in, const int* in_sizes, int n_in,
                              void* d_out, int out_size, void* d_ws, size_t ws_size,
                              hipStream_t stream) {
  const float* x = (const float*)d_in[0];
  const float* G = (const float*)d_in[1];
  const float* H = (const float*)d_in[2];
  const float* bias = (const float*)d_in[3];
  float* out = (float*)d_out;

  __bf16* xb = (__bf16*)d_ws;                                    // 8 MB
  __bf16* Mb = (__bf16*)((char*)d_ws + (size_t)NTOK * NIN * 2);  // 8 MB

  prep_kernel<<<2047 + 2048, 256, 0, stream>>>(x, G, H, xb, Mb);
  gemm_kernel<<<1024, 256, 0, stream>>>(xb, Mb, bias, out);
}